// Round 1
// baseline (273.747 us; speedup 1.0000x reference)
//
#include <hip/hip_runtime.h>
#include <stdint.h>

// ---------------------------------------------------------------------------
// DualGatedRecurrence on MI355X.
// Key insight: reference fwht() is the identity for D=1024 (its butterfly S
// obeys S^2=2I; 10 steps = 32*I, cancelled by d^-0.5). So hproj(x,s) =
// x * prod_i(s_i)  elementwise. Pipeline:
//   k_scaleprod -> chunked scan (A,B,C) -> GEMM1(bf16 MFMA)+epilogue ->
//   rowrms -> GEMM2(bf16 MFMA)+rms-scale epilogue.
// ---------------------------------------------------------------------------

typedef __attribute__((ext_vector_type(8))) short short8;     // 8 bf16 (4 VGPRs)
typedef __attribute__((ext_vector_type(4))) float f32x4;
typedef __attribute__((ext_vector_type(4))) unsigned short ushort4v;

typedef const __attribute__((address_space(1))) unsigned int* as1_u32p;
typedef __attribute__((address_space(3))) unsigned int* as3_u32p;

__device__ __forceinline__ void cp16(const void* g, void* l) {
  // async global->LDS, 16B/lane. LDS dest must be wave-uniform base + lane*16.
  __builtin_amdgcn_global_load_lds((as1_u32p)(uintptr_t)g,
                                   (as3_u32p)(unsigned int)(uintptr_t)l,
                                   16, 0, 0);
}

__device__ __forceinline__ float b2f(unsigned short h) {
  union { unsigned int u; float f; } v; v.u = ((unsigned int)h) << 16; return v.f;
}
__device__ __forceinline__ unsigned short f2b(float f) {
  union { float f; unsigned int u; } v; v.f = f;
  unsigned int r = v.u + 0x7fffu + ((v.u >> 16) & 1u);   // round-nearest-even
  return (unsigned short)(r >> 16);
}
__device__ __forceinline__ float sigmoidf_(float z) { return 1.0f / (1.0f + __expf(-z)); }

// ------------------------- per-channel scale products ----------------------
__global__ __launch_bounds__(256) void k_scaleprod(
    const float* __restrict__ fgs, const float* __restrict__ fvs,
    const float* __restrict__ sgs, const float* __restrict__ svs,
    float* __restrict__ sc) {
  int d = blockIdx.x * 256 + threadIdx.x;
  if (d >= 1024) return;
  float a = 1.f, b = 1.f, c = 1.f, e = 1.f;
#pragma unroll
  for (int i = 0; i < 5; ++i) {
    a *= fgs[i * 1024 + d]; b *= fvs[i * 1024 + d];
    c *= sgs[i * 1024 + d]; e *= svs[i * 1024 + d];
  }
  sc[d] = a; sc[1024 + d] = b; sc[2048 + d] = c; sc[3072 + d] = e;
}

// ------------------------- weight conversions ------------------------------
__global__ __launch_bounds__(256) void k_convert_w(
    const float* __restrict__ fow, const float* __restrict__ sow,
    unsigned short* __restrict__ wcat) {
  int i = (blockIdx.x * 256 + threadIdx.x) * 4;            // < 2097152
  const float* src = (i < 1048576) ? (fow + i) : (sow + (i - 1048576));
  f32x4 v = *(const f32x4*)src;
  ushort4v o = { f2b(v.x), f2b(v.y), f2b(v.z), f2b(v.w) };
  *(ushort4v*)&wcat[i] = o;
}

__global__ __launch_bounds__(256) void k_convert_w2(
    const float* __restrict__ mw, const float* __restrict__ nw,
    unsigned short* __restrict__ w2) {
  int i = (blockIdx.x * 256 + threadIdx.x) * 4;            // < 2097152
  int m = i & 2047;
  f32x4 v = *(const f32x4*)&mw[i];
  f32x4 s = *(const f32x4*)&nw[m];
  ushort4v o = { f2b(v.x * s.x), f2b(v.y * s.y), f2b(v.z * s.z), f2b(v.w * s.w) };
  *(ushort4v*)&w2[i] = o;
}

// ------------------------- chunked gated scan ------------------------------
// sequences s=(b,d): 4096.  T=2048 split into 32 chunks of 64.
// Pass A: per-chunk local scan (zero init) -> P (prod of gates), H (local end).
//         Also emits x in bf16 for the GEMMs.
__global__ __launch_bounds__(256) void k_scanA(
    const float* __restrict__ x, const float* __restrict__ sc,
    float* __restrict__ PF, float* __restrict__ HF,
    float* __restrict__ PS, float* __restrict__ HS,
    unsigned short* __restrict__ xb) {
  int g = blockIdx.x * 256 + threadIdx.x;   // 0..131071
  int d = g & 1023;
  int rest = g >> 10;
  int chunk = rest & 31, b = rest >> 5;
  float fg = sc[d], fv = sc[1024 + d], sg = sc[2048 + d], sv = sc[3072 + d];
  size_t base = ((size_t)(b * 2048 + chunk * 64)) * 1024 + d;
  float pF = 1.f, hF = 0.f, pS = 1.f, hS = 0.f;
#pragma unroll 8
  for (int t = 0; t < 64; ++t) {
    float xv = x[base + (size_t)t * 1024];
    xb[base + (size_t)t * 1024] = f2b(xv);
    float fF = sigmoidf_(xv * fg + 0.5f);
    hF = fF * hF + (1.f - fF) * (xv * fv);
    pF *= fF;
    float fS = 0.85f + 0.15f * sigmoidf_(xv * sg + 0.5f);
    hS = fS * hS + (1.f - fS) * (xv * sv);
    pS *= fS;
  }
  PF[g] = pF; HF[g] = hF; PS[g] = pS; HS[g] = hS;
}

// Pass B: sequential combine across the 32 chunks -> carry-in per chunk.
__global__ __launch_bounds__(256) void k_scanB(
    const float* __restrict__ PF, const float* __restrict__ HF,
    const float* __restrict__ PS, const float* __restrict__ HS,
    float* __restrict__ CF, float* __restrict__ CS) {
  int g = blockIdx.x * 256 + threadIdx.x;   // 0..4095
  int d = g & 1023, b = g >> 10;
  float cF = 0.f, cS = 0.f;
  for (int c = 0; c < 32; ++c) {
    int i = (b * 32 + c) * 1024 + d;
    CF[i] = cF; CS[i] = cS;
    cF = HF[i] + PF[i] * cF;
    cS = HS[i] + PS[i] * cS;
  }
}

// Pass C: recompute local scan with carry-in, emit h_cat (bf16) =
// [fast_h | slow_h] per (b,t) row.
__global__ __launch_bounds__(256) void k_scanC(
    const float* __restrict__ x, const float* __restrict__ sc,
    const float* __restrict__ CF, const float* __restrict__ CS,
    unsigned short* __restrict__ hcat) {
  int g = blockIdx.x * 256 + threadIdx.x;
  int d = g & 1023;
  int rest = g >> 10;
  int chunk = rest & 31, b = rest >> 5;
  float fg = sc[d], fv = sc[1024 + d], sg = sc[2048 + d], sv = sc[3072 + d];
  size_t base = ((size_t)(b * 2048 + chunk * 64)) * 1024 + d;
  float cF = CF[g], cS = CS[g];
  float pF = 1.f, hF = 0.f, pS = 1.f, hS = 0.f;
#pragma unroll 4
  for (int t = 0; t < 64; ++t) {
    float xv = x[base + (size_t)t * 1024];
    float fF = sigmoidf_(xv * fg + 0.5f);
    hF = fF * hF + (1.f - fF) * (xv * fv); pF *= fF;
    float fS = 0.85f + 0.15f * sigmoidf_(xv * sg + 0.5f);
    hS = fS * hS + (1.f - fS) * (xv * sv); pS *= fS;
    size_t bt = (size_t)(b * 2048 + chunk * 64 + t);
    hcat[bt * 2048 + d]        = f2b(hF + pF * cF);
    hcat[bt * 2048 + 1024 + d] = f2b(hS + pS * cS);
  }
}

// ------------------------- row RMS factors ---------------------------------
__global__ __launch_bounds__(256) void k_rowrms(
    const unsigned short* __restrict__ mg, float* __restrict__ rfac) {
  int row = blockIdx.x;
  const unsigned short* p = mg + (size_t)row * 2048;
  float s = 0.f;
  for (int i = threadIdx.x; i < 2048; i += 256) { float v = b2f(p[i]); s += v * v; }
#pragma unroll
  for (int o = 32; o > 0; o >>= 1) s += __shfl_down(s, o);
  __shared__ float red[4];
  if ((threadIdx.x & 63) == 0) red[threadIdx.x >> 6] = s;
  __syncthreads();
  if (threadIdx.x == 0) {
    s = red[0] + red[1] + red[2] + red[3];
    rfac[row] = 1.0f / sqrtf(s * (1.0f / 2048.0f) + 1e-6f);
  }
}

// ------------------------- bf16 MFMA GEMM (B^T form) -----------------------
// C[m,n] = sum_k A[m,k]*B[n,k].  128x128 tile, BK=32, 4 waves, each wave a
// 64x64 subtile as 4x4 MFMA 16x16x32 tiles.  Staging via global_load_lds x16B.
// mode 1: merged[m,n] = bf16( sigmoid(C) * hcat[m,n] )       (N=2048)
// mode 2: out[m,n]    = rfac[m] * C                          (N=1024)
__global__ __launch_bounds__(256) void k_gemm(
    const unsigned short* __restrict__ A, const unsigned short* __restrict__ B,
    int K, int mode,
    const unsigned short* __restrict__ hcat, unsigned short* __restrict__ merged,
    const float* __restrict__ rfac, float* __restrict__ out) {
  __shared__ unsigned short sA[128 * 32];
  __shared__ unsigned short sB[128 * 32];
  const int tid = threadIdx.x;
  const int wv = tid >> 6, ln = tid & 63;
  const int lrow = ln >> 2, lcol = (ln & 3) << 3;   // staging: 16 rows x 4 lanes/row
  const int bm = blockIdx.y * 128, bn = blockIdx.x * 128;

  const unsigned short* gA0 = A + (size_t)(bm + (wv * 2 + 0) * 16 + lrow) * K + lcol;
  const unsigned short* gA1 = A + (size_t)(bm + (wv * 2 + 1) * 16 + lrow) * K + lcol;
  const unsigned short* gB0 = B + (size_t)(bn + (wv * 2 + 0) * 16 + lrow) * K + lcol;
  const unsigned short* gB1 = B + (size_t)(bn + (wv * 2 + 1) * 16 + lrow) * K + lcol;
  unsigned short* lA0 = &sA[(wv * 2 + 0) * 512 + ln * 8];
  unsigned short* lA1 = &sA[(wv * 2 + 1) * 512 + ln * 8];
  unsigned short* lB0 = &sB[(wv * 2 + 0) * 512 + ln * 8];
  unsigned short* lB1 = &sB[(wv * 2 + 1) * 512 + ln * 8];

  const int wm = (wv >> 1) * 64, wn = (wv & 1) * 64;
  const int fr = ln & 15, fq = (ln >> 4) * 8;       // frag row, frag k-offset

  f32x4 acc[4][4];
  const f32x4 z4 = {0.f, 0.f, 0.f, 0.f};
#pragma unroll
  for (int i = 0; i < 4; ++i)
#pragma unroll
    for (int j = 0; j < 4; ++j) acc[i][j] = z4;

  for (int k0 = 0; k0 < K; k0 += 32) {
    cp16(gA0 + k0, lA0);
    cp16(gA1 + k0, lA1);
    cp16(gB0 + k0, lB0);
    cp16(gB1 + k0, lB1);
    __syncthreads();   // compiler drains vmcnt before s_barrier

    short8 af[4], bfr[4];
#pragma unroll
    for (int mi = 0; mi < 4; ++mi)
      af[mi] = *(const short8*)&sA[(wm + mi * 16 + fr) * 32 + fq];
#pragma unroll
    for (int ni = 0; ni < 4; ++ni)
      bfr[ni] = *(const short8*)&sB[(wn + ni * 16 + fr) * 32 + fq];
#pragma unroll
    for (int mi = 0; mi < 4; ++mi)
#pragma unroll
      for (int ni = 0; ni < 4; ++ni)
        acc[mi][ni] = __builtin_amdgcn_mfma_f32_16x16x32_bf16(
            af[mi], bfr[ni], acc[mi][ni], 0, 0, 0);
    __syncthreads();
  }

  // C/D layout: col = lane&15, row = (lane>>4)*4 + reg   [verified m89/m91]
  const int er0 = (ln >> 4) * 4;
  if (mode == 1) {
#pragma unroll
    for (int mi = 0; mi < 4; ++mi) {
#pragma unroll
      for (int ni = 0; ni < 4; ++ni) {
        int n = bn + wn + ni * 16 + fr;
#pragma unroll
        for (int r = 0; r < 4; ++r) {
          int m = bm + wm + mi * 16 + er0 + r;
          size_t idx = (size_t)m * 2048 + n;
          float v = sigmoidf_(acc[mi][ni][r]) * b2f(hcat[idx]);
          merged[idx] = f2b(v);
        }
      }
    }
  } else {
#pragma unroll
    for (int mi = 0; mi < 4; ++mi) {
#pragma unroll
      for (int r = 0; r < 4; ++r) {
        int m = bm + wm + mi * 16 + er0 + r;
        float rf = rfac[m];
#pragma unroll
        for (int ni = 0; ni < 4; ++ni) {
          int n = bn + wn + ni * 16 + fr;
          out[(size_t)m * 1024 + n] = rf * acc[mi][ni][r];
        }
      }
    }
  }
}

// ---------------------------------------------------------------------------
extern "C" void kernel_launch(void* const* d_in, const int* in_sizes, int n_in,
                              void* d_out, int out_size, void* d_ws, size_t ws_size,
                              hipStream_t stream) {
  const float* x   = (const float*)d_in[0];
  const float* fgs = (const float*)d_in[1];
  const float* fvs = (const float*)d_in[2];
  const float* fow = (const float*)d_in[3];
  const float* sgs = (const float*)d_in[4];
  const float* svs = (const float*)d_in[5];
  const float* sow = (const float*)d_in[6];
  const float* mw  = (const float*)d_in[7];
  const float* nw  = (const float*)d_in[8];
  float* out = (float*)d_out;

  char* ws = (char*)d_ws;
  // workspace layout (bytes)
  float* sc   = (float*)(ws + 0);                        // 16 KB
  float* rfac = (float*)(ws + 16384);                    // 32 KB
  float* PF   = (float*)(ws + 49152);                    // 512 KB each
  float* HF   = (float*)(ws + 49152 + 1 * 524288);
  float* PS   = (float*)(ws + 49152 + 2 * 524288);
  float* HS   = (float*)(ws + 49152 + 3 * 524288);
  float* CF   = (float*)(ws + 49152 + 4 * 524288);
  float* CS   = (float*)(ws + 49152 + 5 * 524288);
  unsigned short* xb   = (unsigned short*)(ws + 3194880);   // 16 MB
  unsigned short* wcat = (unsigned short*)(ws + 19972096);  // 4 MB
  unsigned short* w2   = (unsigned short*)(ws + 24166400);  // 4 MB
  unsigned short* hcat = (unsigned short*)(ws + 28360704);  // 32 MB
  unsigned short* mg   = (unsigned short*)(ws + 61915136);  // 32 MB  (end ~91MB)

  k_scaleprod<<<4, 256, 0, stream>>>(fgs, fvs, sgs, svs, sc);
  k_convert_w<<<2048, 256, 0, stream>>>(fow, sow, wcat);
  k_convert_w2<<<2048, 256, 0, stream>>>(mw, nw, w2);
  k_scanA<<<512, 256, 0, stream>>>(x, sc, PF, HF, PS, HS, xb);
  k_scanB<<<16, 256, 0, stream>>>(PF, HF, PS, HS, CF, CS);
  k_scanC<<<512, 256, 0, stream>>>(x, sc, CF, CS, hcat);
  k_gemm<<<dim3(16, 64), 256, 0, stream>>>(xb, wcat, 1024, 1, hcat, mg, nullptr, nullptr);
  k_rowrms<<<8192, 256, 0, stream>>>(mg, rfac);
  k_gemm<<<dim3(8, 64), 256, 0, stream>>>(mg, w2, 2048, 2, nullptr, nullptr, rfac, out);
}

// Round 2
// 272.183 us; speedup vs baseline: 1.0057x; 1.0057x over previous
//
#include <hip/hip_runtime.h>
#include <stdint.h>

// ---------------------------------------------------------------------------
// DualGatedRecurrence on MI355X.
// fwht() in the reference is the identity for D=1024 (butterfly S: S^2=2I;
// 10 steps = 32*I, cancelled by d^-0.5) => hproj(x,s) = x * prod_i(s_i).
// Pipeline: prep (scale products + weight->bf16 + rowsum zero) ->
//   chunked scan (A,B,C) -> GEMM1 (32x32x16 bf16 MFMA, sigmoid*hcat epilogue
//   + fused row-sum-of-squares atomics) -> GEMM2 (rsqrt-scale epilogue).
// GEMM LDS uses XOR swizzle (slot = r*4 + (c ^ ((r+(r>>2))&3))) so 32-row
// ds_read_b128 fragment reads are bank-conflict-free; global_load_lds gathers
// the permuted global addresses (LDS side stays base+lane*16).
// ---------------------------------------------------------------------------

typedef __attribute__((ext_vector_type(8))) short short8;     // 8 bf16
typedef __attribute__((ext_vector_type(16))) float f32x16;
typedef __attribute__((ext_vector_type(4))) float f32x4;
typedef __attribute__((ext_vector_type(4))) unsigned short ushort4v;

typedef const __attribute__((address_space(1))) unsigned int* as1_u32p;
typedef __attribute__((address_space(3))) unsigned int* as3_u32p;

__device__ __forceinline__ void cp16(const void* g, void* l) {
  __builtin_amdgcn_global_load_lds((as1_u32p)(uintptr_t)g,
                                   (as3_u32p)(unsigned int)(uintptr_t)l,
                                   16, 0, 0);
}

__device__ __forceinline__ float b2f(unsigned short h) {
  union { unsigned int u; float f; } v; v.u = ((unsigned int)h) << 16; return v.f;
}
__device__ __forceinline__ unsigned short f2b(float f) {
  union { float f; unsigned int u; } v; v.f = f;
  unsigned int r = v.u + 0x7fffu + ((v.u >> 16) & 1u);   // round-nearest-even
  return (unsigned short)(r >> 16);
}
__device__ __forceinline__ float sigmoidf_(float z) { return 1.0f / (1.0f + __expf(-z)); }

// ------------------------- prep: scales, weights, rowsum zero --------------
__global__ __launch_bounds__(256) void k_prep(
    const float* __restrict__ fgs, const float* __restrict__ fvs,
    const float* __restrict__ sgs, const float* __restrict__ svs,
    const float* __restrict__ fow, const float* __restrict__ sow,
    const float* __restrict__ mw,  const float* __restrict__ nw,
    float* __restrict__ sc, unsigned short* __restrict__ wcat,
    unsigned short* __restrict__ w2, float* __restrict__ rowsum) {
  int g = blockIdx.x * 256 + threadIdx.x;
  if (g < 524288) {                       // wcat = bf16([fast_out_w; slow_out_w])
    int i = g * 4;
    const float* src = (i < 1048576) ? (fow + i) : (sow + (i - 1048576));
    f32x4 v = *(const f32x4*)src;
    ushort4v o = { f2b(v.x), f2b(v.y), f2b(v.z), f2b(v.w) };
    *(ushort4v*)&wcat[i] = o;
  } else if (g < 1048576) {               // w2 = bf16(merge_w * norm_w), [1024][2048]
    int i = (g - 524288) * 4;
    int m = i & 2047;
    f32x4 v = *(const f32x4*)&mw[i];
    f32x4 s = *(const f32x4*)&nw[m];
    ushort4v o = { f2b(v.x * s.x), f2b(v.y * s.y), f2b(v.z * s.z), f2b(v.w * s.w) };
    *(ushort4v*)&w2[i] = o;
  } else if (g < 1049600) {               // per-channel scale products
    int d = g - 1048576;
    float a = 1.f, b = 1.f, c = 1.f, e = 1.f;
#pragma unroll
    for (int i = 0; i < 5; ++i) {
      a *= fgs[i * 1024 + d]; b *= fvs[i * 1024 + d];
      c *= sgs[i * 1024 + d]; e *= svs[i * 1024 + d];
    }
    sc[d] = a; sc[1024 + d] = b; sc[2048 + d] = c; sc[3072 + d] = e;
  } else if (g < 1057792) {               // zero rowsum (ws is poisoned each run)
    rowsum[g - 1049600] = 0.f;
  }
}

// ------------------------- chunked gated scan ------------------------------
__global__ __launch_bounds__(256) void k_scanA(
    const float* __restrict__ x, const float* __restrict__ sc,
    float* __restrict__ PF, float* __restrict__ HF,
    float* __restrict__ PS, float* __restrict__ HS,
    unsigned short* __restrict__ xb) {
  int g = blockIdx.x * 256 + threadIdx.x;   // 0..131071
  int d = g & 1023;
  int rest = g >> 10;
  int chunk = rest & 31, b = rest >> 5;
  float fg = sc[d], fv = sc[1024 + d], sg = sc[2048 + d], sv = sc[3072 + d];
  size_t base = ((size_t)(b * 2048 + chunk * 64)) * 1024 + d;
  float pF = 1.f, hF = 0.f, pS = 1.f, hS = 0.f;
#pragma unroll 8
  for (int t = 0; t < 64; ++t) {
    float xv = x[base + (size_t)t * 1024];
    xb[base + (size_t)t * 1024] = f2b(xv);
    float fF = sigmoidf_(xv * fg + 0.5f);
    hF = fF * hF + (1.f - fF) * (xv * fv); pF *= fF;
    float fS = 0.85f + 0.15f * sigmoidf_(xv * sg + 0.5f);
    hS = fS * hS + (1.f - fS) * (xv * sv); pS *= fS;
  }
  PF[g] = pF; HF[g] = hF; PS[g] = pS; HS[g] = hS;
}

__global__ __launch_bounds__(256) void k_scanB(
    const float* __restrict__ PF, const float* __restrict__ HF,
    const float* __restrict__ PS, const float* __restrict__ HS,
    float* __restrict__ CF, float* __restrict__ CS) {
  int g = blockIdx.x * 256 + threadIdx.x;   // 0..4095
  int d = g & 1023, b = g >> 10;
  float cF = 0.f, cS = 0.f;
  for (int c = 0; c < 32; ++c) {
    int i = (b * 32 + c) * 1024 + d;
    CF[i] = cF; CS[i] = cS;
    cF = HF[i] + PF[i] * cF;
    cS = HS[i] + PS[i] * cS;
  }
}

__global__ __launch_bounds__(256) void k_scanC(
    const float* __restrict__ x, const float* __restrict__ sc,
    const float* __restrict__ CF, const float* __restrict__ CS,
    unsigned short* __restrict__ hcat) {
  int g = blockIdx.x * 256 + threadIdx.x;
  int d = g & 1023;
  int rest = g >> 10;
  int chunk = rest & 31, b = rest >> 5;
  float fg = sc[d], fv = sc[1024 + d], sg = sc[2048 + d], sv = sc[3072 + d];
  size_t base = ((size_t)(b * 2048 + chunk * 64)) * 1024 + d;
  float cF = CF[g], cS = CS[g];
  float pF = 1.f, hF = 0.f, pS = 1.f, hS = 0.f;
#pragma unroll 4
  for (int t = 0; t < 64; ++t) {
    float xv = x[base + (size_t)t * 1024];
    float fF = sigmoidf_(xv * fg + 0.5f);
    hF = fF * hF + (1.f - fF) * (xv * fv); pF *= fF;
    float fS = 0.85f + 0.15f * sigmoidf_(xv * sg + 0.5f);
    hS = fS * hS + (1.f - fS) * (xv * sv); pS *= fS;
    size_t bt = (size_t)(b * 2048 + chunk * 64 + t);
    hcat[bt * 2048 + d]        = f2b(hF + pF * cF);
    hcat[bt * 2048 + 1024 + d] = f2b(hS + pS * cS);
  }
}

// ------------------------- bf16 MFMA GEMM, 32x32x16, swizzled LDS ----------
// C[m,n] = sum_k A[m,k]*B[n,k].  128x128 tile, BK=32, 4 waves, each wave a
// 64x64 subtile as 2x2 MFMA 32x32x16 tiles.
// LDS slot (16B units) for (row r, chunk c): r*4 + (c ^ ((r+(r>>2))&3)).
// mode 1: merged = bf16(sigmoid(C)*hcat); rowsum[m] += sum_n v^2 (atomic)
// mode 2: out = rsqrt(rowsum[m]/2048+1e-6) * C
__global__ __launch_bounds__(256) void k_gemm(
    const unsigned short* __restrict__ A, const unsigned short* __restrict__ B,
    int K, int mode,
    const unsigned short* __restrict__ hcat, unsigned short* __restrict__ merged,
    float* __restrict__ rowsum, float* __restrict__ out) {
  __shared__ __align__(16) unsigned short sA[128 * 32];
  __shared__ __align__(16) unsigned short sB[128 * 32];
  const int tid = threadIdx.x;
  const int wv = tid >> 6, ln = tid & 63;
  const int bm = blockIdx.y * 128, bn = blockIdx.x * 128;

  // --- staging: each cp16 covers 16 rows x 4 chunks; lane ln -> slot R*4+ln
  const int R0 = (wv * 2 + 0) * 16, R1 = (wv * 2 + 1) * 16;
  const int sr0 = R0 + (ln >> 2), sr1 = R1 + (ln >> 2);
  const int cc0 = (ln & 3) ^ ((sr0 + (sr0 >> 2)) & 3);
  const int cc1 = (ln & 3) ^ ((sr1 + (sr1 >> 2)) & 3);
  const unsigned short* gA0 = A + (size_t)(bm + sr0) * K + cc0 * 8;
  const unsigned short* gA1 = A + (size_t)(bm + sr1) * K + cc1 * 8;
  const unsigned short* gB0 = B + (size_t)(bn + sr0) * K + cc0 * 8;
  const unsigned short* gB1 = B + (size_t)(bn + sr1) * K + cc1 * 8;
  unsigned short* lA0 = &sA[R0 * 32 + ln * 8];
  unsigned short* lA1 = &sA[R1 * 32 + ln * 8];
  unsigned short* lB0 = &sB[R0 * 32 + ln * 8];
  unsigned short* lB1 = &sB[R1 * 32 + ln * 8];

  // --- fragment addressing (A: m=lane&31, k=(lane>>5)*8+j; B symmetric)
  const int half = ln >> 5, lm = ln & 31;
  const int am0 = (wv >> 1) * 64 + lm, am1 = am0 + 32;
  const int bq0 = (wv & 1) * 64 + lm, bq1 = bq0 + 32;
  const int ma0 = (am0 + (am0 >> 2)) & 3, ma1 = (am1 + (am1 >> 2)) & 3;
  const int mb0 = (bq0 + (bq0 >> 2)) & 3, mb1 = (bq1 + (bq1 >> 2)) & 3;

  f32x16 acc[2][2];
#pragma unroll
  for (int i = 0; i < 2; ++i)
#pragma unroll
    for (int j = 0; j < 2; ++j)
#pragma unroll
      for (int r = 0; r < 16; ++r) acc[i][j][r] = 0.f;

  for (int k0 = 0; k0 < K; k0 += 32) {
    cp16(gA0 + k0, lA0);
    cp16(gA1 + k0, lA1);
    cp16(gB0 + k0, lB0);
    cp16(gB1 + k0, lB1);
    __syncthreads();
#pragma unroll
    for (int ks = 0; ks < 2; ++ks) {
      const int c = ks * 2 + half;
      short8 a0 = *(const short8*)&sA[(am0 * 4 + (c ^ ma0)) * 8];
      short8 a1 = *(const short8*)&sA[(am1 * 4 + (c ^ ma1)) * 8];
      short8 b0 = *(const short8*)&sB[(bq0 * 4 + (c ^ mb0)) * 8];
      short8 b1 = *(const short8*)&sB[(bq1 * 4 + (c ^ mb1)) * 8];
      acc[0][0] = __builtin_amdgcn_mfma_f32_32x32x16_bf16(a0, b0, acc[0][0], 0, 0, 0);
      acc[0][1] = __builtin_amdgcn_mfma_f32_32x32x16_bf16(a0, b1, acc[0][1], 0, 0, 0);
      acc[1][0] = __builtin_amdgcn_mfma_f32_32x32x16_bf16(a1, b0, acc[1][0], 0, 0, 0);
      acc[1][1] = __builtin_amdgcn_mfma_f32_32x32x16_bf16(a1, b1, acc[1][1], 0, 0, 0);
    }
    __syncthreads();
  }

  // C/D layout (m74/m101): col = lane&31, row = (reg&3) + 8*(reg>>2) + 4*(lane>>5)
  const int wmBase = bm + (wv >> 1) * 64, wnBase = bn + (wv & 1) * 64;
  if (mode == 1) {
#pragma unroll
    for (int ti = 0; ti < 2; ++ti) {
#pragma unroll
      for (int r = 0; r < 16; ++r) {
        const int row = (r & 3) + 8 * (r >> 2) + 4 * half;
        const int m = wmBase + ti * 32 + row;
        float s = 0.f;
#pragma unroll
        for (int tj = 0; tj < 2; ++tj) {
          const int n = wnBase + tj * 32 + lm;
          const size_t idx = (size_t)m * 2048 + n;
          float v = sigmoidf_(acc[ti][tj][r]) * b2f(hcat[idx]);
          merged[idx] = f2b(v);
          s += v * v;
        }
#pragma unroll
        for (int o = 1; o < 32; o <<= 1) s += __shfl_xor(s, o);
        if (lm == 0) atomicAdd(&rowsum[m], s);
      }
    }
  } else {
#pragma unroll
    for (int ti = 0; ti < 2; ++ti) {
#pragma unroll
      for (int r = 0; r < 16; ++r) {
        const int row = (r & 3) + 8 * (r >> 2) + 4 * half;
        const int m = wmBase + ti * 32 + row;
        const float rf = rsqrtf(rowsum[m] * (1.0f / 2048.0f) + 1e-6f);
#pragma unroll
        for (int tj = 0; tj < 2; ++tj) {
          const int n = wnBase + tj * 32 + lm;
          out[(size_t)m * 1024 + n] = rf * acc[ti][tj][r];
        }
      }
    }
  }
}

// ---------------------------------------------------------------------------
extern "C" void kernel_launch(void* const* d_in, const int* in_sizes, int n_in,
                              void* d_out, int out_size, void* d_ws, size_t ws_size,
                              hipStream_t stream) {
  const float* x   = (const float*)d_in[0];
  const float* fgs = (const float*)d_in[1];
  const float* fvs = (const float*)d_in[2];
  const float* fow = (const float*)d_in[3];
  const float* sgs = (const float*)d_in[4];
  const float* svs = (const float*)d_in[5];
  const float* sow = (const float*)d_in[6];
  const float* mw  = (const float*)d_in[7];
  const float* nw  = (const float*)d_in[8];
  float* out = (float*)d_out;

  char* ws = (char*)d_ws;
  float* sc     = (float*)(ws + 0);                      // 16 KB
  float* rowsum = (float*)(ws + 16384);                  // 32 KB
  float* PF     = (float*)(ws + 49152);                  // 512 KB each
  float* HF     = (float*)(ws + 49152 + 1 * 524288);
  float* PS     = (float*)(ws + 49152 + 2 * 524288);
  float* HS     = (float*)(ws + 49152 + 3 * 524288);
  float* CF     = (float*)(ws + 49152 + 4 * 524288);
  float* CS     = (float*)(ws + 49152 + 5 * 524288);
  unsigned short* xb   = (unsigned short*)(ws + 3194880);   // 16 MB
  unsigned short* wcat = (unsigned short*)(ws + 19972096);  // 4 MB
  unsigned short* w2   = (unsigned short*)(ws + 24166400);  // 4 MB
  unsigned short* hcat = (unsigned short*)(ws + 28360704);  // 32 MB
  unsigned short* mg   = (unsigned short*)(ws + 61915136);  // 32 MB (end ~91MB)

  k_prep<<<4132, 256, 0, stream>>>(fgs, fvs, sgs, svs, fow, sow, mw, nw,
                                   sc, wcat, w2, rowsum);
  k_scanA<<<512, 256, 0, stream>>>(x, sc, PF, HF, PS, HS, xb);
  k_scanB<<<16, 256, 0, stream>>>(PF, HF, PS, HS, CF, CS);
  k_scanC<<<512, 256, 0, stream>>>(x, sc, CF, CS, hcat);
  k_gemm<<<dim3(16, 64), 256, 0, stream>>>(xb, wcat, 1024, 1, hcat, mg, rowsum, nullptr);
  k_gemm<<<dim3(8, 64), 256, 0, stream>>>(mg, w2, 2048, 2, nullptr, nullptr, rowsum, out);
}

// Round 3
// 257.631 us; speedup vs baseline: 1.0626x; 1.0565x over previous
//
#include <hip/hip_runtime.h>
#include <stdint.h>

// ---------------------------------------------------------------------------
// DualGatedRecurrence on MI355X.
// fwht() in the reference is the identity for D=1024 (butterfly S: S^2=2I;
// 10 steps = 32*I, cancelled by d^-0.5) => hproj(x,s) = x * prod_i(s_i).
// Pipeline: prep (weights->bf16, rowsum zero) -> scanA (local chunk scans,
//   x->bf16) -> scanC (carry + full scan -> hcat bf16) ->
//   GEMM1 (16x16x32 bf16 MFMA, BK=64, sigmoid*hcat epilogue + fused row
//   sum-of-squares atomics) -> GEMM2 (64x128 tile, rsqrt-scale epilogue).
// GEMM LDS XOR swizzle: 16B-chunk slot = chunk ^ (row&7) at 128B row stride
// -> conflict-free ds_read_b128 fragment reads; global_load_lds fetches the
// permuted global chunks (LDS dest stays wave-uniform base + lane*16).
// ---------------------------------------------------------------------------

typedef __attribute__((ext_vector_type(8))) short short8;     // 8 bf16
typedef __attribute__((ext_vector_type(4))) float f32x4;
typedef __attribute__((ext_vector_type(4))) unsigned short ushort4v;

typedef const __attribute__((address_space(1))) unsigned int* as1_u32p;
typedef __attribute__((address_space(3))) unsigned int* as3_u32p;

__device__ __forceinline__ void cp16(const void* g, void* l) {
  __builtin_amdgcn_global_load_lds((as1_u32p)(uintptr_t)g,
                                   (as3_u32p)(unsigned int)(uintptr_t)l,
                                   16, 0, 0);
}

__device__ __forceinline__ float b2f(unsigned short h) {
  union { unsigned int u; float f; } v; v.u = ((unsigned int)h) << 16; return v.f;
}
__device__ __forceinline__ unsigned short f2b(float f) {
  union { float f; unsigned int u; } v; v.f = f;
  unsigned int r = v.u + 0x7fffu + ((v.u >> 16) & 1u);   // round-nearest-even
  return (unsigned short)(r >> 16);
}
__device__ __forceinline__ float sigmoidf_(float z) { return 1.0f / (1.0f + __expf(-z)); }

// ------------------------- prep: weights -> bf16, rowsum zero --------------
__global__ __launch_bounds__(256) void k_prep(
    const float* __restrict__ fow, const float* __restrict__ sow,
    const float* __restrict__ mw,  const float* __restrict__ nw,
    unsigned short* __restrict__ wcat, unsigned short* __restrict__ w2,
    float* __restrict__ rowsum) {
  int g = blockIdx.x * 256 + threadIdx.x;
  if (g < 524288) {                       // wcat = bf16([fast_out_w; slow_out_w])
    int i = g * 4;
    const float* src = (i < 1048576) ? (fow + i) : (sow + (i - 1048576));
    f32x4 v = *(const f32x4*)src;
    ushort4v o = { f2b(v.x), f2b(v.y), f2b(v.z), f2b(v.w) };
    *(ushort4v*)&wcat[i] = o;
  } else if (g < 1048576) {               // w2 = bf16(merge_w * norm_w), [1024][2048]
    int i = (g - 524288) * 4;
    int m = i & 2047;
    f32x4 v = *(const f32x4*)&mw[i];
    f32x4 s = *(const f32x4*)&nw[m];
    ushort4v o = { f2b(v.x * s.x), f2b(v.y * s.y), f2b(v.z * s.z), f2b(v.w * s.w) };
    *(ushort4v*)&w2[i] = o;
  } else if (g < 1056768) {               // zero rowsum (ws poisoned each run)
    rowsum[g - 1048576] = 0.f;
  }
}

// ------------------------- chunked gated scan ------------------------------
// sequences (b,d): 4096.  T=2048 in 32 chunks of 64.
// Pass A: per-chunk local scan -> P (gate products), H (local end state);
//         emits x as bf16 for GEMM1.
__global__ __launch_bounds__(256) void k_scanA(
    const float* __restrict__ x,
    const float* __restrict__ fgs, const float* __restrict__ fvs,
    const float* __restrict__ sgs, const float* __restrict__ svs,
    float* __restrict__ PF, float* __restrict__ HF,
    float* __restrict__ PS, float* __restrict__ HS,
    unsigned short* __restrict__ xb) {
  int g = blockIdx.x * 256 + threadIdx.x;   // 0..131071
  int d = g & 1023;
  int rest = g >> 10;
  int chunk = rest & 31, b = rest >> 5;
  float fg = 1.f, fv = 1.f, sg = 1.f, sv = 1.f;
#pragma unroll
  for (int i = 0; i < 5; ++i) {
    fg *= fgs[i * 1024 + d]; fv *= fvs[i * 1024 + d];
    sg *= sgs[i * 1024 + d]; sv *= svs[i * 1024 + d];
  }
  size_t base = ((size_t)(b * 2048 + chunk * 64)) * 1024 + d;
  float pF = 1.f, hF = 0.f, pS = 1.f, hS = 0.f;
#pragma unroll 8
  for (int t = 0; t < 64; ++t) {
    float xv = x[base + (size_t)t * 1024];
    xb[base + (size_t)t * 1024] = f2b(xv);
    float fF = sigmoidf_(xv * fg + 0.5f);
    hF = fF * hF + (1.f - fF) * (xv * fv); pF *= fF;
    float fS = 0.85f + 0.15f * sigmoidf_(xv * sg + 0.5f);
    hS = fS * hS + (1.f - fS) * (xv * sv); pS *= fS;
  }
  PF[g] = pF; HF[g] = hF; PS[g] = pS; HS[g] = hS;
}

// Pass C: recompute carry from P/H prefix (cheap, L2-resident), then full
// local scan with carry, emitting h_cat bf16 = [fast_h | slow_h].
__global__ __launch_bounds__(256) void k_scanC(
    const float* __restrict__ x,
    const float* __restrict__ fgs, const float* __restrict__ fvs,
    const float* __restrict__ sgs, const float* __restrict__ svs,
    const float* __restrict__ PF, const float* __restrict__ HF,
    const float* __restrict__ PS, const float* __restrict__ HS,
    unsigned short* __restrict__ hcat) {
  int g = blockIdx.x * 256 + threadIdx.x;
  int d = g & 1023;
  int rest = g >> 10;
  int chunk = rest & 31, b = rest >> 5;   // uniform per block (256 | 1024)
  float fg = 1.f, fv = 1.f, sg = 1.f, sv = 1.f;
#pragma unroll
  for (int i = 0; i < 5; ++i) {
    fg *= fgs[i * 1024 + d]; fv *= fvs[i * 1024 + d];
    sg *= sgs[i * 1024 + d]; sv *= svs[i * 1024 + d];
  }
  float cF = 0.f, cS = 0.f;
  for (int c = 0; c < chunk; ++c) {       // carry-in for this chunk
    int i = (b * 32 + c) * 1024 + d;
    cF = HF[i] + PF[i] * cF;
    cS = HS[i] + PS[i] * cS;
  }
  size_t base = ((size_t)(b * 2048 + chunk * 64)) * 1024 + d;
  float pF = 1.f, hF = 0.f, pS = 1.f, hS = 0.f;
#pragma unroll 4
  for (int t = 0; t < 64; ++t) {
    float xv = x[base + (size_t)t * 1024];
    float fF = sigmoidf_(xv * fg + 0.5f);
    hF = fF * hF + (1.f - fF) * (xv * fv); pF *= fF;
    float fS = 0.85f + 0.15f * sigmoidf_(xv * sg + 0.5f);
    hS = fS * hS + (1.f - fS) * (xv * sv); pS *= fS;
    size_t bt = (size_t)(b * 2048 + chunk * 64 + t);
    hcat[bt * 2048 + d]        = f2b(hF + pF * cF);
    hcat[bt * 2048 + 1024 + d] = f2b(hS + pS * cS);
  }
}

// ------------------------- bf16 MFMA GEMM, 16x16x32, BK=64, swizzled -------
// C[m,n] = sum_k A[m,k]*B[n,k].  Block tile (2*WM) x (2*WN), 4 waves in 2x2,
// each wave a WM x WN subtile of 16x16 MFMA tiles.  BK=64 (2 sub-steps per
// barrier pair).  LDS row stride 64 elts (128B = 8 x 16B chunks), physical
// chunk slot = logical_chunk ^ (row & 7)  -> conflict-free b128 frag reads.
// MODE 1: merged = bf16(sigmoid(C)*hcat); rowsum[m] += sum_n v^2 (atomic)
// MODE 2: out = rsqrt(rowsum[m]/2048 + 1e-6) * C
template <int WM, int WN, int MODE>
__global__ __launch_bounds__(256, 4) void k_gemm(
    const unsigned short* __restrict__ A, const unsigned short* __restrict__ B,
    const int K,
    const unsigned short* __restrict__ hcat, unsigned short* __restrict__ merged,
    float* __restrict__ rowsum, float* __restrict__ out) {
  constexpr int BM = 2 * WM, BN = 2 * WN;
  constexpr int RA = BM / 32;             // cp16 rounds per wave (8 rows each)
  constexpr int RB = BN / 32;
  constexpr int AM = WM / 16, BT = WN / 16;
  __shared__ __align__(16) unsigned short sA[BM * 64];
  __shared__ __align__(16) unsigned short sB[BN * 64];
  const int tid = threadIdx.x, wv = tid >> 6, ln = tid & 63;
  const int bm = blockIdx.y * BM, bn = blockIdx.x * BN;

  // staging: round j covers 8 rows x 8 chunks (1KB). row&7 == ln>>3 always.
  const int srow = ln >> 3;                       // 0..7 within round
  const int clog = (ln & 7) ^ srow;               // swizzled logical chunk
  const unsigned short* gA[RA]; unsigned short* lA[RA];
  const unsigned short* gB[RB]; unsigned short* lB[RB];
#pragma unroll
  for (int j = 0; j < RA; ++j) {
    const int R0 = wv * (BM / 4) + j * 8;
    gA[j] = A + (size_t)(bm + R0 + srow) * K + clog * 8;
    lA[j] = &sA[R0 * 64 + ln * 8];
  }
#pragma unroll
  for (int j = 0; j < RB; ++j) {
    const int R0 = wv * (BN / 4) + j * 8;
    gB[j] = B + (size_t)(bn + R0 + srow) * K + clog * 8;
    lB[j] = &sB[R0 * 64 + ln * 8];
  }

  // fragment addressing: A[m=ln&15][k=(ln>>4)*8+j], sub-step adds 32 to k.
  const int fr = ln & 15, fq = ln >> 4;           // frag row, chunk base 0..3
  const int wm = (wv >> 1) * WM, wn = (wv & 1) * WN;

  f32x4 acc[AM][BT];
  const f32x4 z4 = {0.f, 0.f, 0.f, 0.f};
#pragma unroll
  for (int i = 0; i < AM; ++i)
#pragma unroll
    for (int j = 0; j < BT; ++j) acc[i][j] = z4;

  for (int k0 = 0; k0 < K; k0 += 64) {
#pragma unroll
    for (int j = 0; j < RA; ++j) cp16(gA[j] + k0, lA[j]);
#pragma unroll
    for (int j = 0; j < RB; ++j) cp16(gB[j] + k0, lB[j]);
    __syncthreads();
#pragma unroll
    for (int sub = 0; sub < 2; ++sub) {
      short8 af[AM], bf[BT];
#pragma unroll
      for (int mi = 0; mi < AM; ++mi) {
        const int row = wm + mi * 16 + fr;
        const int slot = (fq + sub * 4) ^ (row & 7);
        af[mi] = *(const short8*)&sA[row * 64 + slot * 8];
      }
#pragma unroll
      for (int ni = 0; ni < BT; ++ni) {
        const int row = wn + ni * 16 + fr;
        const int slot = (fq + sub * 4) ^ (row & 7);
        bf[ni] = *(const short8*)&sB[row * 64 + slot * 8];
      }
#pragma unroll
      for (int mi = 0; mi < AM; ++mi)
#pragma unroll
        for (int ni = 0; ni < BT; ++ni)
          acc[mi][ni] = __builtin_amdgcn_mfma_f32_16x16x32_bf16(
              af[mi], bf[ni], acc[mi][ni], 0, 0, 0);
    }
    __syncthreads();
  }

  // C/D layout: col = lane&15, row = (lane>>4)*4 + reg   [verified m89/m91]
  const int er0 = fq * 4;
  if (MODE == 1) {
#pragma unroll
    for (int mi = 0; mi < AM; ++mi) {
#pragma unroll
      for (int r = 0; r < 4; ++r) {
        const int m = bm + wm + mi * 16 + er0 + r;
        float s = 0.f;
#pragma unroll
        for (int ni = 0; ni < BT; ++ni) {
          const int n = bn + wn + ni * 16 + fr;
          const size_t idx = (size_t)m * 2048 + n;
          float v = sigmoidf_(acc[mi][ni][r]) * b2f(hcat[idx]);
          merged[idx] = f2b(v);
          s += v * v;
        }
        s += __shfl_xor(s, 1); s += __shfl_xor(s, 2);
        s += __shfl_xor(s, 4); s += __shfl_xor(s, 8);
        if (fr == 0) atomicAdd(&rowsum[m], s);
      }
    }
  } else {
#pragma unroll
    for (int mi = 0; mi < AM; ++mi) {
#pragma unroll
      for (int r = 0; r < 4; ++r) {
        const int m = bm + wm + mi * 16 + er0 + r;
        const float rf = rsqrtf(rowsum[m] * (1.0f / 2048.0f) + 1e-6f);
#pragma unroll
        for (int ni = 0; ni < BT; ++ni) {
          const int n = bn + wn + ni * 16 + fr;
          out[(size_t)m * 1024 + n] = rf * acc[mi][ni][r];
        }
      }
    }
  }
}

// ---------------------------------------------------------------------------
extern "C" void kernel_launch(void* const* d_in, const int* in_sizes, int n_in,
                              void* d_out, int out_size, void* d_ws, size_t ws_size,
                              hipStream_t stream) {
  const float* x   = (const float*)d_in[0];
  const float* fgs = (const float*)d_in[1];
  const float* fvs = (const float*)d_in[2];
  const float* fow = (const float*)d_in[3];
  const float* sgs = (const float*)d_in[4];
  const float* svs = (const float*)d_in[5];
  const float* sow = (const float*)d_in[6];
  const float* mw  = (const float*)d_in[7];
  const float* nw  = (const float*)d_in[8];
  float* out = (float*)d_out;

  char* ws = (char*)d_ws;
  float* rowsum = (float*)(ws + 0);                      // 32 KB
  float* PF     = (float*)(ws + 32768);                  // 512 KB each
  float* HF     = (float*)(ws + 32768 + 1 * 524288);
  float* PS     = (float*)(ws + 32768 + 2 * 524288);
  float* HS     = (float*)(ws + 32768 + 3 * 524288);
  unsigned short* xb   = (unsigned short*)(ws + 2129920);   // 16 MB
  unsigned short* wcat = (unsigned short*)(ws + 18907136);  // 4 MB
  unsigned short* w2   = (unsigned short*)(ws + 23101440);  // 4 MB
  unsigned short* hcat = (unsigned short*)(ws + 27295744);  // 32 MB
  unsigned short* mg   = (unsigned short*)(ws + 60850176);  // 32 MB (end ~90MB)

  k_prep<<<4128, 256, 0, stream>>>(fow, sow, mw, nw, wcat, w2, rowsum);
  k_scanA<<<512, 256, 0, stream>>>(x, fgs, fvs, sgs, svs, PF, HF, PS, HS, xb);
  k_scanC<<<512, 256, 0, stream>>>(x, fgs, fvs, sgs, svs, PF, HF, PS, HS, hcat);
  // GEMM1: M=8192 (bt), N=2048 (out ch), K=1024
  k_gemm<64, 64, 1><<<dim3(16, 64), 256, 0, stream>>>(
      xb, wcat, 1024, hcat, mg, rowsum, nullptr);
  // GEMM2: M=8192 (bt), N=1024 (d), K=2048; 64x128 tile -> 1024 blocks
  k_gemm<32, 64, 2><<<dim3(8, 128), 256, 0, stream>>>(
      mg, w2, 2048, nullptr, nullptr, rowsum, out);
}

// Round 4
// 249.254 us; speedup vs baseline: 1.0983x; 1.0336x over previous
//
#include <hip/hip_runtime.h>
#include <stdint.h>

// ---------------------------------------------------------------------------
// DualGatedRecurrence on MI355X.
// fwht() in the reference is the identity for D=1024 (butterfly S: S^2=2I;
// 10 steps = 32*I, cancelled by d^-0.5) => hproj(x,s) = x * prod_i(s_i).
// Pipeline (5 dispatches):
//   scanA+prep (local chunk scans, x->bf16, weights->bf16, rowsum zero)
//   -> scanC (carry from chunk P/H + rescan from bf16 x -> hcat)
//   -> GEMM1 (16x16x32 bf16 MFMA, BK=64, sigmoid*hcat epilogue + fused
//      row sum-of-squares atomics)
//   -> GEMM2 (rsqrt-scale epilogue).
// GEMM LDS XOR swizzle: 16B-chunk slot = chunk ^ (row&7) at 128B row stride
// -> conflict-free ds_read_b128 (verified: SQ_LDS_BANK_CONFLICT==0 in R3).
// GEMM grid uses XCD-aware remap (n%8 == band%8) so all column-tiles of an
// A row-band share one XCD's L2 (A band fits 4MiB L2) — cuts A refetch.
// ---------------------------------------------------------------------------

typedef __attribute__((ext_vector_type(8))) short short8;     // 8 bf16
typedef __attribute__((ext_vector_type(4))) float f32x4;
typedef __attribute__((ext_vector_type(4))) unsigned short ushort4v;

typedef const __attribute__((address_space(1))) unsigned int* as1_u32p;
typedef __attribute__((address_space(3))) unsigned int* as3_u32p;

__device__ __forceinline__ void cp16(const void* g, void* l) {
  __builtin_amdgcn_global_load_lds((as1_u32p)(uintptr_t)g,
                                   (as3_u32p)(unsigned int)(uintptr_t)l,
                                   16, 0, 0);
}

__device__ __forceinline__ float b2f(unsigned short h) {
  union { unsigned int u; float f; } v; v.u = ((unsigned int)h) << 16; return v.f;
}
__device__ __forceinline__ unsigned short f2b(float f) {
  union { float f; unsigned int u; } v; v.f = f;
  unsigned int r = v.u + 0x7fffu + ((v.u >> 16) & 1u);   // round-nearest-even
  return (unsigned short)(r >> 16);
}
__device__ __forceinline__ float sigmoidf_(float z) { return 1.0f / (1.0f + __expf(-z)); }

// ---------------- scanA (blocks 0..511) + prep (blocks 512..4639) ----------
// scan: sequences (b,d): 4096, T=2048 in 32 chunks of 64. Local scan ->
// P (gate products), H (local end state); emits x as bf16.
// prep: wcat=bf16([fow;sow]), w2=bf16(mw*nw), rowsum=0.
__global__ __launch_bounds__(256) void k_scanA(
    const float* __restrict__ x,
    const float* __restrict__ fgs, const float* __restrict__ fvs,
    const float* __restrict__ sgs, const float* __restrict__ svs,
    const float* __restrict__ fow, const float* __restrict__ sow,
    const float* __restrict__ mw,  const float* __restrict__ nw,
    float* __restrict__ PF, float* __restrict__ HF,
    float* __restrict__ PS, float* __restrict__ HS,
    unsigned short* __restrict__ xb,
    unsigned short* __restrict__ wcat, unsigned short* __restrict__ w2,
    float* __restrict__ rowsum) {
  if (blockIdx.x >= 512) {                 // ---- prep part ----
    int g = (blockIdx.x - 512) * 256 + threadIdx.x;   // 0..1056767
    if (g < 524288) {
      int i = g * 4;
      const float* src = (i < 1048576) ? (fow + i) : (sow + (i - 1048576));
      f32x4 v = *(const f32x4*)src;
      ushort4v o = { f2b(v.x), f2b(v.y), f2b(v.z), f2b(v.w) };
      *(ushort4v*)&wcat[i] = o;
    } else if (g < 1048576) {
      int i = (g - 524288) * 4;
      int m = i & 2047;
      f32x4 v = *(const f32x4*)&mw[i];
      f32x4 s = *(const f32x4*)&nw[m];
      ushort4v o = { f2b(v.x * s.x), f2b(v.y * s.y), f2b(v.z * s.z), f2b(v.w * s.w) };
      *(ushort4v*)&w2[i] = o;
    } else if (g < 1056768) {
      rowsum[g - 1048576] = 0.f;
    }
    return;
  }
  // ---- scan part ----
  int g = blockIdx.x * 256 + threadIdx.x;   // 0..131071
  int d = g & 1023;
  int rest = g >> 10;
  int chunk = rest & 31, b = rest >> 5;
  float fg = 1.f, fv = 1.f, sg = 1.f, sv = 1.f;
#pragma unroll
  for (int i = 0; i < 5; ++i) {
    fg *= fgs[i * 1024 + d]; fv *= fvs[i * 1024 + d];
    sg *= sgs[i * 1024 + d]; sv *= svs[i * 1024 + d];
  }
  size_t base = ((size_t)(b * 2048 + chunk * 64)) * 1024 + d;
  float pF = 1.f, hF = 0.f, pS = 1.f, hS = 0.f;
#pragma unroll 8
  for (int t = 0; t < 64; ++t) {
    float xv = x[base + (size_t)t * 1024];
    xb[base + (size_t)t * 1024] = f2b(xv);
    float fF = sigmoidf_(xv * fg + 0.5f);
    hF = fF * hF + (1.f - fF) * (xv * fv); pF *= fF;
    float fS = 0.85f + 0.15f * sigmoidf_(xv * sg + 0.5f);
    hS = fS * hS + (1.f - fS) * (xv * sv); pS *= fS;
  }
  PF[g] = pF; HF[g] = hF; PS[g] = pS; HS[g] = hS;
}

// ---------------- scanC: carry + rescan (from bf16 x) -> hcat --------------
__global__ __launch_bounds__(256) void k_scanC(
    const unsigned short* __restrict__ xb,
    const float* __restrict__ fgs, const float* __restrict__ fvs,
    const float* __restrict__ sgs, const float* __restrict__ svs,
    const float* __restrict__ PF, const float* __restrict__ HF,
    const float* __restrict__ PS, const float* __restrict__ HS,
    unsigned short* __restrict__ hcat) {
  int g = blockIdx.x * 256 + threadIdx.x;
  int d = g & 1023;
  int rest = g >> 10;
  int chunk = rest & 31, b = rest >> 5;   // block-uniform
  float fg = 1.f, fv = 1.f, sg = 1.f, sv = 1.f;
#pragma unroll
  for (int i = 0; i < 5; ++i) {
    fg *= fgs[i * 1024 + d]; fv *= fvs[i * 1024 + d];
    sg *= sgs[i * 1024 + d]; sv *= svs[i * 1024 + d];
  }
  // carry-in: combine chunk aggregates 0..chunk-1 (L2-resident), 4x batched
  float cF = 0.f, cS = 0.f;
  {
    int base_i = b * 32 * 1024 + d;
    int c = 0;
    for (; c + 4 <= chunk; c += 4) {
      float pf0 = PF[base_i + (c + 0) * 1024], hf0 = HF[base_i + (c + 0) * 1024];
      float pf1 = PF[base_i + (c + 1) * 1024], hf1 = HF[base_i + (c + 1) * 1024];
      float pf2 = PF[base_i + (c + 2) * 1024], hf2 = HF[base_i + (c + 2) * 1024];
      float pf3 = PF[base_i + (c + 3) * 1024], hf3 = HF[base_i + (c + 3) * 1024];
      float ps0 = PS[base_i + (c + 0) * 1024], hs0 = HS[base_i + (c + 0) * 1024];
      float ps1 = PS[base_i + (c + 1) * 1024], hs1 = HS[base_i + (c + 1) * 1024];
      float ps2 = PS[base_i + (c + 2) * 1024], hs2 = HS[base_i + (c + 2) * 1024];
      float ps3 = PS[base_i + (c + 3) * 1024], hs3 = HS[base_i + (c + 3) * 1024];
      cF = hf0 + pf0 * cF; cF = hf1 + pf1 * cF;
      cF = hf2 + pf2 * cF; cF = hf3 + pf3 * cF;
      cS = hs0 + ps0 * cS; cS = hs1 + ps1 * cS;
      cS = hs2 + ps2 * cS; cS = hs3 + ps3 * cS;
    }
    for (; c < chunk; ++c) {
      int i = base_i + c * 1024;
      cF = HF[i] + PF[i] * cF;
      cS = HS[i] + PS[i] * cS;
    }
  }
  size_t base = ((size_t)(b * 2048 + chunk * 64)) * 1024 + d;
  float pF = 1.f, hF = 0.f, pS = 1.f, hS = 0.f;
#pragma unroll 8
  for (int t = 0; t < 64; ++t) {
    float xv = b2f(xb[base + (size_t)t * 1024]);
    float fF = sigmoidf_(xv * fg + 0.5f);
    hF = fF * hF + (1.f - fF) * (xv * fv); pF *= fF;
    float fS = 0.85f + 0.15f * sigmoidf_(xv * sg + 0.5f);
    hS = fS * hS + (1.f - fS) * (xv * sv); pS *= fS;
    size_t bt = (size_t)(b * 2048 + chunk * 64 + t);
    hcat[bt * 2048 + d]        = f2b(hF + pF * cF);
    hcat[bt * 2048 + 1024 + d] = f2b(hS + pS * cS);
  }
}

// ------------------------- bf16 MFMA GEMM, 16x16x32, BK=64, swizzled -------
// C[m,n] = sum_k A[m,k]*B[n,k].  Block tile (2*WM)x(2*WN), 4 waves 2x2, each
// wave WMxWN of 16x16 MFMA tiles, BK=64 (2 sub-steps per barrier pair).
// LDS row stride 64 elts; 16B-chunk slot = chunk ^ (row&7): conflict-free.
// Grid: 1D, XCD remap: col = (n>>3)&(2^CB-1); band = (n&7)|((n>>(3+CB))<<3)
// so n%8 (the XCD round-robin index) equals band%8.
// MODE 1: merged = bf16(sigmoid(C)*hcat); rowsum[m] += sum_n v^2 (atomic)
// MODE 2: out = rsqrt(rowsum[m]/2048 + 1e-6) * C
template <int WM, int WN, int MODE, int CB>
__global__ __launch_bounds__(256, 4) void k_gemm(
    const unsigned short* __restrict__ A, const unsigned short* __restrict__ B,
    const int K,
    const unsigned short* __restrict__ hcat, unsigned short* __restrict__ merged,
    float* __restrict__ rowsum, float* __restrict__ out) {
  constexpr int BM = 2 * WM, BN = 2 * WN;
  constexpr int RA = BM / 32, RB = BN / 32;   // cp16 rounds (8 rows each)
  constexpr int AM = WM / 16, BT = WN / 16;
  __shared__ __align__(16) unsigned short sA[BM * 64];
  __shared__ __align__(16) unsigned short sB[BN * 64];
  const int tid = threadIdx.x, wv = tid >> 6, ln = tid & 63;
  const int n_ = blockIdx.x;
  const int col = (n_ >> 3) & ((1 << CB) - 1);
  const int band = (n_ & 7) | ((n_ >> (3 + CB)) << 3);
  const int bm = band * BM, bn = col * BN;

  const int srow = ln >> 3;                       // 0..7 within round
  const int clog = (ln & 7) ^ srow;               // swizzled logical chunk
  const unsigned short* gA[RA]; unsigned short* lA[RA];
  const unsigned short* gB[RB]; unsigned short* lB[RB];
#pragma unroll
  for (int j = 0; j < RA; ++j) {
    const int R0 = wv * (BM / 4) + j * 8;
    gA[j] = A + (size_t)(bm + R0 + srow) * K + clog * 8;
    lA[j] = &sA[R0 * 64 + ln * 8];
  }
#pragma unroll
  for (int j = 0; j < RB; ++j) {
    const int R0 = wv * (BN / 4) + j * 8;
    gB[j] = B + (size_t)(bn + R0 + srow) * K + clog * 8;
    lB[j] = &sB[R0 * 64 + ln * 8];
  }

  const int fr = ln & 15, fq = ln >> 4;           // frag row, chunk base 0..3
  const int wm = (wv >> 1) * WM, wn = (wv & 1) * WN;

  f32x4 acc[AM][BT];
  const f32x4 z4 = {0.f, 0.f, 0.f, 0.f};
#pragma unroll
  for (int i = 0; i < AM; ++i)
#pragma unroll
    for (int j = 0; j < BT; ++j) acc[i][j] = z4;

  for (int k0 = 0; k0 < K; k0 += 64) {
#pragma unroll
    for (int j = 0; j < RA; ++j) cp16(gA[j] + k0, lA[j]);
#pragma unroll
    for (int j = 0; j < RB; ++j) cp16(gB[j] + k0, lB[j]);
    __syncthreads();
#pragma unroll
    for (int sub = 0; sub < 2; ++sub) {
      short8 af[AM], bf[BT];
#pragma unroll
      for (int mi = 0; mi < AM; ++mi) {
        const int row = wm + mi * 16 + fr;
        const int slot = (fq + sub * 4) ^ (row & 7);
        af[mi] = *(const short8*)&sA[row * 64 + slot * 8];
      }
#pragma unroll
      for (int ni = 0; ni < BT; ++ni) {
        const int row = wn + ni * 16 + fr;
        const int slot = (fq + sub * 4) ^ (row & 7);
        bf[ni] = *(const short8*)&sB[row * 64 + slot * 8];
      }
#pragma unroll
      for (int mi = 0; mi < AM; ++mi)
#pragma unroll
        for (int ni = 0; ni < BT; ++ni)
          acc[mi][ni] = __builtin_amdgcn_mfma_f32_16x16x32_bf16(
              af[mi], bf[ni], acc[mi][ni], 0, 0, 0);
    }
    __syncthreads();
  }

  // C/D layout: col = lane&15, row = (lane>>4)*4 + reg   [verified m89/m91]
  const int er0 = fq * 4;
  if (MODE == 1) {
#pragma unroll
    for (int mi = 0; mi < AM; ++mi) {
#pragma unroll
      for (int r = 0; r < 4; ++r) {
        const int m = bm + wm + mi * 16 + er0 + r;
        float s = 0.f;
#pragma unroll
        for (int ni = 0; ni < BT; ++ni) {
          const int n = bn + wn + ni * 16 + fr;
          const size_t idx = (size_t)m * 2048 + n;
          float v = sigmoidf_(acc[mi][ni][r]) * b2f(hcat[idx]);
          merged[idx] = f2b(v);
          s += v * v;
        }
        s += __shfl_xor(s, 1); s += __shfl_xor(s, 2);
        s += __shfl_xor(s, 4); s += __shfl_xor(s, 8);
        if (fr == 0) atomicAdd(&rowsum[m], s);
      }
    }
  } else {
#pragma unroll
    for (int mi = 0; mi < AM; ++mi) {
#pragma unroll
      for (int r = 0; r < 4; ++r) {
        const int m = bm + wm + mi * 16 + er0 + r;
        const float rf = rsqrtf(rowsum[m] * (1.0f / 2048.0f) + 1e-6f);
#pragma unroll
        for (int ni = 0; ni < BT; ++ni) {
          const int n = bn + wn + ni * 16 + fr;
          out[(size_t)m * 1024 + n] = rf * acc[mi][ni][r];
        }
      }
    }
  }
}

// ---------------------------------------------------------------------------
extern "C" void kernel_launch(void* const* d_in, const int* in_sizes, int n_in,
                              void* d_out, int out_size, void* d_ws, size_t ws_size,
                              hipStream_t stream) {
  const float* x   = (const float*)d_in[0];
  const float* fgs = (const float*)d_in[1];
  const float* fvs = (const float*)d_in[2];
  const float* fow = (const float*)d_in[3];
  const float* sgs = (const float*)d_in[4];
  const float* svs = (const float*)d_in[5];
  const float* sow = (const float*)d_in[6];
  const float* mw  = (const float*)d_in[7];
  const float* nw  = (const float*)d_in[8];
  float* out = (float*)d_out;

  char* ws = (char*)d_ws;
  float* rowsum = (float*)(ws + 0);                      // 32 KB
  float* PF     = (float*)(ws + 32768);                  // 512 KB each
  float* HF     = (float*)(ws + 32768 + 1 * 524288);
  float* PS     = (float*)(ws + 32768 + 2 * 524288);
  float* HS     = (float*)(ws + 32768 + 3 * 524288);
  unsigned short* xb   = (unsigned short*)(ws + 2129920);   // 16 MB
  unsigned short* wcat = (unsigned short*)(ws + 18907136);  // 4 MB
  unsigned short* w2   = (unsigned short*)(ws + 23101440);  // 4 MB
  unsigned short* hcat = (unsigned short*)(ws + 27295744);  // 32 MB
  unsigned short* mg   = (unsigned short*)(ws + 60850176);  // 32 MB (end ~90MB)

  // scan (blocks 0..511) + weight prep (blocks 512..4639)
  k_scanA<<<4640, 256, 0, stream>>>(x, fgs, fvs, sgs, svs, fow, sow, mw, nw,
                                    PF, HF, PS, HS, xb, wcat, w2, rowsum);
  k_scanC<<<512, 256, 0, stream>>>(xb, fgs, fvs, sgs, svs, PF, HF, PS, HS, hcat);
  // GEMM1: M=8192, N=2048, K=1024; tile 128x128; grid 64 bands x 16 cols
  k_gemm<64, 64, 1, 4><<<1024, 256, 0, stream>>>(
      xb, wcat, 1024, hcat, mg, rowsum, nullptr);
  // GEMM2: M=8192, N=1024, K=2048; tile 64x128; grid 128 bands x 8 cols
  k_gemm<32, 64, 2, 3><<<1024, 256, 0, stream>>>(
      mg, w2, 2048, nullptr, nullptr, rowsum, out);
}

// Round 5
// 218.211 us; speedup vs baseline: 1.2545x; 1.1423x over previous
//
#include <hip/hip_runtime.h>
#include <stdint.h>

// ---------------------------------------------------------------------------
// DualGatedRecurrence on MI355X.
// fwht() in the reference is the identity for D=1024 (butterfly S: S^2=2I;
// 10 steps = 32*I, cancelled by d^-0.5) => hproj(x,s) = x * prod_i(s_i).
// Pipeline (4 dispatches):
//   scanA+prep: per-chunk local scans (C=64 chunks of 32, d2-vectorized,
//     STORE-FREE scan part so loads pipeline) -> P,H aggregates; prep
//     converts weights to bf16 and zeroes rowsum.
//   scanC: carry prefix from P/H (L2-resident) + full rescan from f32 x;
//     emits xb (bf16 x) and hcat = [fast_h | slow_h] bf16.
//   GEMM1: 16x16x32 bf16 MFMA, BK=64, XOR-swizzled LDS (conflict-free,
//     verified R3), XCD-aware remap; epilogue sigmoid*hcat + fused row
//     sum-of-squares atomics.
//   GEMM2: same structure, rsqrt row-scale epilogue.
// ---------------------------------------------------------------------------

typedef __attribute__((ext_vector_type(8))) short short8;     // 8 bf16
typedef __attribute__((ext_vector_type(4))) float f32x4;
typedef __attribute__((ext_vector_type(2))) float f32x2;
typedef __attribute__((ext_vector_type(4))) unsigned short ushort4v;
typedef __attribute__((ext_vector_type(2))) unsigned short ushort2v;

typedef const __attribute__((address_space(1))) unsigned int* as1_u32p;
typedef __attribute__((address_space(3))) unsigned int* as3_u32p;

__device__ __forceinline__ void cp16(const void* g, void* l) {
  __builtin_amdgcn_global_load_lds((as1_u32p)(uintptr_t)g,
                                   (as3_u32p)(unsigned int)(uintptr_t)l,
                                   16, 0, 0);
}

__device__ __forceinline__ float b2f(unsigned short h) {
  union { unsigned int u; float f; } v; v.u = ((unsigned int)h) << 16; return v.f;
}
__device__ __forceinline__ unsigned short f2b(float f) {
  union { float f; unsigned int u; } v; v.f = f;
  unsigned int r = v.u + 0x7fffu + ((v.u >> 16) & 1u);   // round-nearest-even
  return (unsigned short)(r >> 16);
}
// fast sigmoid: hw exp + hw rcp (saves the ~9-op precise-div sequence)
__device__ __forceinline__ float sigmoidf_(float z) {
  return __builtin_amdgcn_rcpf(1.0f + __expf(-z));
}

// ---------------- scanA (blocks 0..511) + prep (blocks 512..4639) ----------
// scan: (b, chunk, d-pair): 4 x 64 x 512 threads. chunk = 32 t-steps.
// Pure-read: emits only P (gate products) and H (local end states).
__global__ __launch_bounds__(256) void k_scanA(
    const float* __restrict__ x,
    const float* __restrict__ fgs, const float* __restrict__ fvs,
    const float* __restrict__ sgs, const float* __restrict__ svs,
    const float* __restrict__ fow, const float* __restrict__ sow,
    const float* __restrict__ mw,  const float* __restrict__ nw,
    float* __restrict__ PF, float* __restrict__ HF,
    float* __restrict__ PS, float* __restrict__ HS,
    unsigned short* __restrict__ wcat, unsigned short* __restrict__ w2,
    float* __restrict__ rowsum) {
  if (blockIdx.x >= 512) {                 // ---- prep part ----
    int g = (blockIdx.x - 512) * 256 + threadIdx.x;   // 0..1056767
    if (g < 524288) {
      int i = g * 4;
      const float* src = (i < 1048576) ? (fow + i) : (sow + (i - 1048576));
      f32x4 v = *(const f32x4*)src;
      ushort4v o = { f2b(v.x), f2b(v.y), f2b(v.z), f2b(v.w) };
      *(ushort4v*)&wcat[i] = o;
    } else if (g < 1048576) {
      int i = (g - 524288) * 4;
      int m = i & 2047;
      f32x4 v = *(const f32x4*)&mw[i];
      f32x4 s = *(const f32x4*)&nw[m];
      ushort4v o = { f2b(v.x * s.x), f2b(v.y * s.y), f2b(v.z * s.z), f2b(v.w * s.w) };
      *(ushort4v*)&w2[i] = o;
    } else if (g < 1056768) {
      rowsum[g - 1048576] = 0.f;
    }
    return;
  }
  // ---- scan part (store-free) ----
  int g = blockIdx.x * 256 + threadIdx.x;   // 0..131071
  int d0 = (g & 511) << 1;
  int rest = g >> 9;
  int chunk = rest & 63, b = rest >> 6;
  float fg0 = 1.f, fg1 = 1.f, fv0 = 1.f, fv1 = 1.f;
  float sg0 = 1.f, sg1 = 1.f, sv0 = 1.f, sv1 = 1.f;
#pragma unroll
  for (int i = 0; i < 5; ++i) {
    f32x2 a = *(const f32x2*)&fgs[i * 1024 + d0]; fg0 *= a.x; fg1 *= a.y;
    f32x2 bq = *(const f32x2*)&fvs[i * 1024 + d0]; fv0 *= bq.x; fv1 *= bq.y;
    f32x2 c = *(const f32x2*)&sgs[i * 1024 + d0]; sg0 *= c.x; sg1 *= c.y;
    f32x2 e = *(const f32x2*)&svs[i * 1024 + d0]; sv0 *= e.x; sv1 *= e.y;
  }
  size_t base = ((size_t)(b * 2048 + chunk * 32)) * 1024 + d0;
  float pF0 = 1.f, hF0 = 0.f, pS0 = 1.f, hS0 = 0.f;
  float pF1 = 1.f, hF1 = 0.f, pS1 = 1.f, hS1 = 0.f;
#pragma unroll 8
  for (int t = 0; t < 32; ++t) {
    f32x2 xv = *(const f32x2*)&x[base + (size_t)t * 1024];
    float fF0 = sigmoidf_(xv.x * fg0 + 0.5f);
    hF0 = fF0 * hF0 + (1.f - fF0) * (xv.x * fv0); pF0 *= fF0;
    float fS0 = 0.85f + 0.15f * sigmoidf_(xv.x * sg0 + 0.5f);
    hS0 = fS0 * hS0 + (1.f - fS0) * (xv.x * sv0); pS0 *= fS0;
    float fF1 = sigmoidf_(xv.y * fg1 + 0.5f);
    hF1 = fF1 * hF1 + (1.f - fF1) * (xv.y * fv1); pF1 *= fF1;
    float fS1 = 0.85f + 0.15f * sigmoidf_(xv.y * sg1 + 0.5f);
    hS1 = fS1 * hS1 + (1.f - fS1) * (xv.y * sv1); pS1 *= fS1;
  }
  int idx = (b * 64 + chunk) * 1024 + d0;
  *(f32x2*)&PF[idx] = f32x2{pF0, pF1};
  *(f32x2*)&HF[idx] = f32x2{hF0, hF1};
  *(f32x2*)&PS[idx] = f32x2{pS0, pS1};
  *(f32x2*)&HS[idx] = f32x2{hS0, hS1};
}

// ---------------- scanC: carry prefix + rescan -> xb (bf16), hcat ----------
__global__ __launch_bounds__(256) void k_scanC(
    const float* __restrict__ x,
    const float* __restrict__ fgs, const float* __restrict__ fvs,
    const float* __restrict__ sgs, const float* __restrict__ svs,
    const float* __restrict__ PF, const float* __restrict__ HF,
    const float* __restrict__ PS, const float* __restrict__ HS,
    unsigned short* __restrict__ xb, unsigned short* __restrict__ hcat) {
  int g = blockIdx.x * 256 + threadIdx.x;
  int d0 = (g & 511) << 1;
  int rest = g >> 9;
  int chunk = rest & 63, b = rest >> 6;   // block-uniform
  float fg0 = 1.f, fg1 = 1.f, fv0 = 1.f, fv1 = 1.f;
  float sg0 = 1.f, sg1 = 1.f, sv0 = 1.f, sv1 = 1.f;
#pragma unroll
  for (int i = 0; i < 5; ++i) {
    f32x2 a = *(const f32x2*)&fgs[i * 1024 + d0]; fg0 *= a.x; fg1 *= a.y;
    f32x2 bq = *(const f32x2*)&fvs[i * 1024 + d0]; fv0 *= bq.x; fv1 *= bq.y;
    f32x2 c = *(const f32x2*)&sgs[i * 1024 + d0]; sg0 *= c.x; sg1 *= c.y;
    f32x2 e = *(const f32x2*)&svs[i * 1024 + d0]; sv0 *= e.x; sv1 *= e.y;
  }
  // carry-in: combine chunk aggregates 0..chunk-1 (L2-resident), 4x batched
  float cF0 = 0.f, cF1 = 0.f, cS0 = 0.f, cS1 = 0.f;
  {
    int base_i = b * 64 * 1024 + d0;
    int c = 0;
    for (; c + 4 <= chunk; c += 4) {
      f32x2 pf[4], hf[4], ps[4], hs[4];
#pragma unroll
      for (int j = 0; j < 4; ++j) {
        int i = base_i + (c + j) * 1024;
        pf[j] = *(const f32x2*)&PF[i]; hf[j] = *(const f32x2*)&HF[i];
        ps[j] = *(const f32x2*)&PS[i]; hs[j] = *(const f32x2*)&HS[i];
      }
#pragma unroll
      for (int j = 0; j < 4; ++j) {
        cF0 = hf[j].x + pf[j].x * cF0; cF1 = hf[j].y + pf[j].y * cF1;
        cS0 = hs[j].x + ps[j].x * cS0; cS1 = hs[j].y + ps[j].y * cS1;
      }
    }
    for (; c < chunk; ++c) {
      int i = base_i + c * 1024;
      f32x2 pf = *(const f32x2*)&PF[i], hf = *(const f32x2*)&HF[i];
      f32x2 ps = *(const f32x2*)&PS[i], hs = *(const f32x2*)&HS[i];
      cF0 = hf.x + pf.x * cF0; cF1 = hf.y + pf.y * cF1;
      cS0 = hs.x + ps.x * cS0; cS1 = hs.y + ps.y * cS1;
    }
  }
  size_t base = ((size_t)(b * 2048 + chunk * 32)) * 1024 + d0;
  float pF0 = 1.f, hF0 = 0.f, pS0 = 1.f, hS0 = 0.f;
  float pF1 = 1.f, hF1 = 0.f, pS1 = 1.f, hS1 = 0.f;
#pragma unroll 4
  for (int t = 0; t < 32; ++t) {
    f32x2 xv = *(const f32x2*)&x[base + (size_t)t * 1024];
    *(ushort2v*)&xb[base + (size_t)t * 1024] = ushort2v{f2b(xv.x), f2b(xv.y)};
    float fF0 = sigmoidf_(xv.x * fg0 + 0.5f);
    hF0 = fF0 * hF0 + (1.f - fF0) * (xv.x * fv0); pF0 *= fF0;
    float fS0 = 0.85f + 0.15f * sigmoidf_(xv.x * sg0 + 0.5f);
    hS0 = fS0 * hS0 + (1.f - fS0) * (xv.x * sv0); pS0 *= fS0;
    float fF1 = sigmoidf_(xv.y * fg1 + 0.5f);
    hF1 = fF1 * hF1 + (1.f - fF1) * (xv.y * fv1); pF1 *= fF1;
    float fS1 = 0.85f + 0.15f * sigmoidf_(xv.y * sg1 + 0.5f);
    hS1 = fS1 * hS1 + (1.f - fS1) * (xv.y * sv1); pS1 *= fS1;
    size_t bt = (size_t)(b * 2048 + chunk * 32 + t);
    *(ushort2v*)&hcat[bt * 2048 + d0] =
        ushort2v{f2b(hF0 + pF0 * cF0), f2b(hF1 + pF1 * cF1)};
    *(ushort2v*)&hcat[bt * 2048 + 1024 + d0] =
        ushort2v{f2b(hS0 + pS0 * cS0), f2b(hS1 + pS1 * cS1)};
  }
}

// ------------------------- bf16 MFMA GEMM, 16x16x32, BK=64, swizzled -------
// C[m,n] = sum_k A[m,k]*B[n,k].  Block tile (2*WM)x(2*WN), 4 waves 2x2, each
// wave WMxWN of 16x16 MFMA tiles, BK=64 (2 sub-steps per barrier pair).
// LDS row stride 64 elts; 16B-chunk slot = chunk ^ (row&7): conflict-free.
// Grid 1D, XCD remap: col=(n>>3)&(2^CB-1); band=(n&7)|((n>>(3+CB))<<3).
// MODE 1: merged = bf16(sigmoid(C)*hcat); rowsum[m] += sum_n v^2 (atomic)
// MODE 2: out = rsqrt(rowsum[m]/2048 + 1e-6) * C
template <int WM, int WN, int MODE, int CB>
__global__ __launch_bounds__(256, 4) void k_gemm(
    const unsigned short* __restrict__ A, const unsigned short* __restrict__ B,
    const int K,
    const unsigned short* __restrict__ hcat, unsigned short* __restrict__ merged,
    float* __restrict__ rowsum, float* __restrict__ out) {
  constexpr int BM = 2 * WM, BN = 2 * WN;
  constexpr int RA = BM / 32, RB = BN / 32;   // cp16 rounds (8 rows each)
  constexpr int AM = WM / 16, BT = WN / 16;
  __shared__ __align__(16) unsigned short sA[BM * 64];
  __shared__ __align__(16) unsigned short sB[BN * 64];
  const int tid = threadIdx.x, wv = tid >> 6, ln = tid & 63;
  const int n_ = blockIdx.x;
  const int col = (n_ >> 3) & ((1 << CB) - 1);
  const int band = (n_ & 7) | ((n_ >> (3 + CB)) << 3);
  const int bm = band * BM, bn = col * BN;

  const int srow = ln >> 3;                       // 0..7 within round
  const int clog = (ln & 7) ^ srow;               // swizzled logical chunk
  const unsigned short* gA[RA]; unsigned short* lA[RA];
  const unsigned short* gB[RB]; unsigned short* lB[RB];
#pragma unroll
  for (int j = 0; j < RA; ++j) {
    const int R0 = wv * (BM / 4) + j * 8;
    gA[j] = A + (size_t)(bm + R0 + srow) * K + clog * 8;
    lA[j] = &sA[R0 * 64 + ln * 8];
  }
#pragma unroll
  for (int j = 0; j < RB; ++j) {
    const int R0 = wv * (BN / 4) + j * 8;
    gB[j] = B + (size_t)(bn + R0 + srow) * K + clog * 8;
    lB[j] = &sB[R0 * 64 + ln * 8];
  }

  const int fr = ln & 15, fq = ln >> 4;           // frag row, chunk base 0..3
  const int wm = (wv >> 1) * WM, wn = (wv & 1) * WN;

  f32x4 acc[AM][BT];
  const f32x4 z4 = {0.f, 0.f, 0.f, 0.f};
#pragma unroll
  for (int i = 0; i < AM; ++i)
#pragma unroll
    for (int j = 0; j < BT; ++j) acc[i][j] = z4;

  for (int k0 = 0; k0 < K; k0 += 64) {
#pragma unroll
    for (int j = 0; j < RA; ++j) cp16(gA[j] + k0, lA[j]);
#pragma unroll
    for (int j = 0; j < RB; ++j) cp16(gB[j] + k0, lB[j]);
    __syncthreads();
#pragma unroll
    for (int sub = 0; sub < 2; ++sub) {
      short8 af[AM], bf[BT];
#pragma unroll
      for (int mi = 0; mi < AM; ++mi) {
        const int row = wm + mi * 16 + fr;
        const int slot = (fq + sub * 4) ^ (row & 7);
        af[mi] = *(const short8*)&sA[row * 64 + slot * 8];
      }
#pragma unroll
      for (int ni = 0; ni < BT; ++ni) {
        const int row = wn + ni * 16 + fr;
        const int slot = (fq + sub * 4) ^ (row & 7);
        bf[ni] = *(const short8*)&sB[row * 64 + slot * 8];
      }
#pragma unroll
      for (int mi = 0; mi < AM; ++mi)
#pragma unroll
        for (int ni = 0; ni < BT; ++ni)
          acc[mi][ni] = __builtin_amdgcn_mfma_f32_16x16x32_bf16(
              af[mi], bf[ni], acc[mi][ni], 0, 0, 0);
    }
    __syncthreads();
  }

  // C/D layout: col = lane&15, row = (lane>>4)*4 + reg   [verified m89/m91]
  const int er0 = fq * 4;
  if (MODE == 1) {
#pragma unroll
    for (int mi = 0; mi < AM; ++mi) {
#pragma unroll
      for (int r = 0; r < 4; ++r) {
        const int m = bm + wm + mi * 16 + er0 + r;
        float s = 0.f;
#pragma unroll
        for (int ni = 0; ni < BT; ++ni) {
          const int n = bn + wn + ni * 16 + fr;
          const size_t idx = (size_t)m * 2048 + n;
          float v = sigmoidf_(acc[mi][ni][r]) * b2f(hcat[idx]);
          merged[idx] = f2b(v);
          s += v * v;
        }
        s += __shfl_xor(s, 1); s += __shfl_xor(s, 2);
        s += __shfl_xor(s, 4); s += __shfl_xor(s, 8);
        if (fr == 0) atomicAdd(&rowsum[m], s);
      }
    }
  } else {
#pragma unroll
    for (int mi = 0; mi < AM; ++mi) {
#pragma unroll
      for (int r = 0; r < 4; ++r) {
        const int m = bm + wm + mi * 16 + er0 + r;
        const float rf = rsqrtf(rowsum[m] * (1.0f / 2048.0f) + 1e-6f);
#pragma unroll
        for (int ni = 0; ni < BT; ++ni) {
          const int n = bn + wn + ni * 16 + fr;
          out[(size_t)m * 1024 + n] = rf * acc[mi][ni][r];
        }
      }
    }
  }
}

// ---------------------------------------------------------------------------
extern "C" void kernel_launch(void* const* d_in, const int* in_sizes, int n_in,
                              void* d_out, int out_size, void* d_ws, size_t ws_size,
                              hipStream_t stream) {
  const float* x   = (const float*)d_in[0];
  const float* fgs = (const float*)d_in[1];
  const float* fvs = (const float*)d_in[2];
  const float* fow = (const float*)d_in[3];
  const float* sgs = (const float*)d_in[4];
  const float* svs = (const float*)d_in[5];
  const float* sow = (const float*)d_in[6];
  const float* mw  = (const float*)d_in[7];
  const float* nw  = (const float*)d_in[8];
  float* out = (float*)d_out;

  char* ws = (char*)d_ws;
  float* rowsum = (float*)(ws + 0);                         // 32 KB
  unsigned short* xb   = (unsigned short*)(ws + 32768);     // 16 MB
  unsigned short* wcat = (unsigned short*)(ws + 16809984);  // 4 MB
  unsigned short* w2   = (unsigned short*)(ws + 21004288);  // 4 MB
  unsigned short* hcat = (unsigned short*)(ws + 25198592);  // 32 MB
  unsigned short* mg   = (unsigned short*)(ws + 58753024);  // 32 MB (end ~92MB)
  // P/H (1 MB each) alias the mg region: P/H are dead before GEMM1 writes mg.
  float* PF = (float*)(ws + 58753024);
  float* HF = (float*)(ws + 58753024 + 1 * 1048576);
  float* PS = (float*)(ws + 58753024 + 2 * 1048576);
  float* HS = (float*)(ws + 58753024 + 3 * 1048576);

  // scan (blocks 0..511, store-free) + weight prep (blocks 512..4639)
  k_scanA<<<4640, 256, 0, stream>>>(x, fgs, fvs, sgs, svs, fow, sow, mw, nw,
                                    PF, HF, PS, HS, wcat, w2, rowsum);
  k_scanC<<<512, 256, 0, stream>>>(x, fgs, fvs, sgs, svs, PF, HF, PS, HS,
                                   xb, hcat);
  // GEMM1: M=8192, N=2048, K=1024; tile 128x128; 64 bands x 16 cols
  k_gemm<64, 64, 1, 4><<<1024, 256, 0, stream>>>(
      xb, wcat, 1024, hcat, mg, rowsum, nullptr);
  // GEMM2: M=8192, N=1024, K=2048; tile 64x128; 128 bands x 8 cols
  k_gemm<32, 64, 2, 3><<<1024, 256, 0, stream>>>(
      mg, w2, 2048, nullptr, nullptr, rowsum, out);
}